// Round 7
// baseline (1203.355 us; speedup 1.0000x reference)
//
#include <hip/hip_runtime.h>
#include <cstdint>

typedef short short8 __attribute__((ext_vector_type(8)));
typedef float f32x16 __attribute__((ext_vector_type(16)));

// Problem constants
#define NB 4
#define NN 4096
#define ND 576
#define BIGI 0x7FFFFFFF

// ws layout: A_hi (bf16) [b][tile32][kc18][512 chunks of 16B] = 9437184 shorts,
// then A_lo same size; then (float units):
#define INVN_OFF 9437184
#define CANDV_OFF 9439488
// candidate lists: per b, row n has cnt(n)=16+(n>>8) lists of 3 (v,idx).
// lists per b: L = 96256. CANDV = 4*96256*3 = 1155072 floats.
#define LPB 96256
#define CANDI_OFF 10594560
// CANDI: 1155072 u16 = 577536 float-equiv -> total 11172096 floats = 44.7MB
// Chunk swizzle (baked into layout): chunk g = r*4 + c', source chunk
// c = c' ^ ((r>>1)&3).

#define MFMA __builtin_amdgcn_mfma_f32_32x32x16_bf16

__device__ __forceinline__ unsigned short f2bf(float f) {
    unsigned u = __float_as_uint(f);
    u += 0x7FFFu + ((u >> 16) & 1u);   // round-to-nearest-even
    return (unsigned short)(u >> 16);
}

__device__ __forceinline__ void gload_lds16(const void* g, void* l) {
    __builtin_amdgcn_global_load_lds(
        (const __attribute__((address_space(1))) void*)g,
        (__attribute__((address_space(3))) void*)l, 16, 0, 0);
}

// packed candidate-list base for (b, row n): sum_{q<n} (16 + q>>8)
__device__ __forceinline__ int list_base(int b, int n) {
    const int K = n >> 8;
    return b * LPB + 16 * n + 128 * K * (K - 1) + (n & 255) * K;
}

// Exact jax top_k comparator: bigger value wins; tie -> smaller index wins.
__device__ __forceinline__ void insert_cmp(float v, int m,
    float& v0, int& i0, float& v1, int& i1, float& v2, int& i2) {
    bool beat2 = (v > v2) || (v == v2 && m < i2);
    if (beat2) {
        bool beat1 = (v > v1) || (v == v1 && m < i1);
        if (beat1) {
            v2 = v1; i2 = i1;
            bool beat0 = (v > v0) || (v == v0 && m < i0);
            if (beat0) { v1 = v0; i1 = i0; v0 = v; i0 = m; }
            else       { v1 = v;  i1 = m; }
        } else { v2 = v; i2 = m; }
    }
}

// Kernel 1: per-(b,c) windowed sums of x^2 -> inv norms for the 9 kernel offsets.
__global__ __launch_bounds__(64) void norm_kernel(const float* __restrict__ x,
                                                  float* __restrict__ ws) {
    const int bc = blockIdx.x;          // b*64 + c
    const int lane = threadIdx.x;       // = column w
    const float* xp = x + ((size_t)bc << 12);
    float colsum = 0.f, v0 = 0.f, v63 = 0.f;
    for (int h = 0; h < 64; ++h) {
        const float val = xp[(h << 6) + lane];
        const float sq = val * val;
        colsum += sq;
        if (h == 0)  v0 = sq;
        if (h == 63) v63 = sq;
    }
    float total = colsum, row0 = v0, row63 = v63;
    #pragma unroll
    for (int o = 32; o > 0; o >>= 1) {
        total += __shfl_xor(total, o);
        row0  += __shfl_xor(row0, o);
        row63 += __shfl_xor(row63, o);
    }
    const float col0  = __shfl(colsum, 0);
    const float col63 = __shfl(colsum, 63);
    const float c00 = __shfl(v0, 0),  c0e = __shfl(v0, 63);
    const float ce0 = __shfl(v63, 0), cee = __shfl(v63, 63);
    if (lane < 9) {
        const int dh = lane / 3 - 1, dw = lane % 3 - 1;
        float S = total;
        if (dh == 1)  S -= row0;
        if (dh == -1) S -= row63;
        if (dw == 1)  S -= col0;
        if (dw == -1) S -= col63;
        if (dh == 1  && dw == 1)  S += c00;
        if (dh == 1  && dw == -1) S += c0e;
        if (dh == -1 && dw == 1)  S += ce0;
        if (dh == -1 && dw == -1) S += cee;
        float nrm = fmaxf(sqrtf(S), 1e-12f);
        ws[INVN_OFF + bc * 9 + lane] = 1.0f / nrm;
    }
}

// Kernel 2: split-bf16 materialization with baked chunk swizzle.
// blockIdx = (b*32+nt)*18+kc. Region = 512 chunks of 16B (8 bf16).
__global__ __launch_bounds__(256) void mat_kernel(const float* __restrict__ x,
                                                  float* __restrict__ ws) {
    const int bi = blockIdx.x;             // 2304 blocks
    const int b = bi / 576;
    const int rem = bi - b * 576;
    const int nt = rem / 18;
    const int kc = rem - nt * 18;
    unsigned short* AH = (unsigned short*)ws;
    unsigned short* AL = AH + 9437184;
    const float* invn = ws + INVN_OFF + b * 576;
    const int tid = threadIdx.x;
    #pragma unroll
    for (int hf2 = 0; hf2 < 2; ++hf2) {
        const int g = tid + hf2 * 256;     // output chunk 0..511
        const int row = g >> 2, cp = g & 3;
        const int c = cp ^ ((row >> 1) & 3);    // source chunk (swizzle)
        const int k0 = c * 8;
        const int n = nt * 128 + row;
        const int h = n >> 6, wc = n & 63;
        union { unsigned short us[8]; float4 f4; } uh, ul;
        #pragma unroll
        for (int j = 0; j < 8; ++j) {
            const int d = kc * 32 + k0 + j;
            const int ch = d / 9;
            const int p = d - ch * 9;
            const int r = h + p / 3 - 1, s2 = wc + p % 3 - 1;
            float val = 0.f;
            if ((unsigned)r < 64u && (unsigned)s2 < 64u)
                val = x[((size_t)(b * 64 + ch) << 12) + (r << 6) + s2];
            val *= invn[d];
            const unsigned short hb = f2bf(val);
            const float hfv = __uint_as_float(((unsigned)hb) << 16);
            const unsigned short lb = f2bf(val - hfv);
            uh.us[j] = hb; ul.us[j] = lb;
        }
        ((float4*)AH)[(size_t)bi * 512 + g] = uh.f4;
        ((float4*)AL)[(size_t)bi * 512 + g] = ul.f4;
    }
}

__device__ __forceinline__ short8 ldfrag(const short* p) {
    union { short8 s8; float4 f4; } u;
    u.f4 = *(const float4*)p;
    return u.s8;
}

// Kernel 3: upper-triangular R = A^T A via split-bf16 MFMA, fused top-3 with
// mirrored (m-side) emission. Grid 1088 = b(4) x 272 tiles (nt <= 2*mp+1).
// Block: 128 n-rows x 256 m-cols, 4 waves, wave tile = 128n x 64m.
// Coverage proof: pair (a,b) n-side-covered iff tile (a>>7, b>>8) exists;
// otherwise mirror tile (b>>7, a>>8) exists and has mp > nt>>1 (emits m-side).
// Exactly-once: both-emission would need a>>8 > b>>8 AND a>>7 <= 2(b>>8)+1 ->
// contradiction. Mirrored values are bitwise identical (same products, k-order).
__global__ void __launch_bounds__(256, 2) gram_kernel(float* ws) {
    __shared__ short sm[24576];   // 48KB: AnH(8K) AnL(8K) AmH(16K) AmL(16K) bytes
    const int t = blockIdx.x;
    const int b = t / 272;
    const int r = t - b * 272;
    int mp = 0;
    while ((mp + 1) * (mp + 2) <= r) ++mp;    // block-uniform scalar loop
    const int nt = r - mp * (mp + 1);         // nt in [0, 2*mp+2)
    const int tid = threadIdx.x;
    const int w = tid >> 6, lane = tid & 63;
    const int l31 = lane & 31, kh2 = lane >> 5;

    const unsigned short* AH = (const unsigned short*)ws;
    const unsigned short* AL = AH + 9437184;

    // LDS region bases (shorts)
    const int AnH = 0, AnL = 4096, AmH = 8192, AmL = 16384;   // Am: t0 then t1 (+4096)
    const int nRegBase = (b * 32 + nt) * 18;
    const int mReg0 = (b * 32 + 2 * mp) * 18;
    const int mReg1 = mReg0 + 18;

    // per-lane frag LDS offsets (shorts), swizzled chunk addressing:
    // frag(row, c) at row*32 + (c ^ ((row>>1)&3))*8, c = kh2 + 2h
    int aoff[2][2];      // [mi][h] Am (within 16K region incl. tile select)
    int boff[4][2];      // [ni][h] An
    #pragma unroll
    for (int mi = 0; mi < 2; ++mi)
        #pragma unroll
        for (int h = 0; h < 2; ++h) {
            const int row = w * 64 + mi * 32 + l31;      // 0..255
            const int rl = row & 127, rt = row >> 7;
            const int c = kh2 + 2 * h;
            aoff[mi][h] = rt * 4096 + rl * 32 + (c ^ ((rl >> 1) & 3)) * 8;
        }
    #pragma unroll
    for (int ni = 0; ni < 4; ++ni)
        #pragma unroll
        for (int h = 0; h < 2; ++h) {
            const int row = ni * 32 + l31;               // 0..127
            const int c = kh2 + 2 * h;
            boff[ni][h] = row * 32 + (c ^ ((row >> 1) & 3)) * 8;
        }

    float t0v[4], t1v[4], t2v[4];
    int   t0i[4], t1i[4], t2i[4];
    #pragma unroll
    for (int i = 0; i < 4; ++i) {
        t0v[i] = t1v[i] = t2v[i] = -INFINITY;
        t0i[i] = t1i[i] = t2i[i] = BIGI;
    }

    f32x16 acc[2][4];
    #pragma unroll
    for (int mi = 0; mi < 2; ++mi)
        #pragma unroll
        for (int ni = 0; ni < 4; ++ni)
            #pragma unroll
            for (int e = 0; e < 16; ++e) acc[mi][ni][e] = 0.f;

    for (int kc = 0; kc < 18; ++kc) {
        __syncthreads();
        // stage 6 x 8KB regions; per wave 2 instrs/region, 1KB each
        {
            const int lo0 = (w * 2) * 512, lo1 = (w * 2 + 1) * 512;   // LDS shorts
            const int go0 = lo0 + lane * 8, go1 = lo1 + lane * 8;     // global shorts
            const unsigned short* gAnH = AH + (size_t)(nRegBase + kc) * 4096;
            const unsigned short* gAnL = AL + (size_t)(nRegBase + kc) * 4096;
            const unsigned short* gM0H = AH + (size_t)(mReg0 + kc) * 4096;
            const unsigned short* gM1H = AH + (size_t)(mReg1 + kc) * 4096;
            const unsigned short* gM0L = AL + (size_t)(mReg0 + kc) * 4096;
            const unsigned short* gM1L = AL + (size_t)(mReg1 + kc) * 4096;
            gload_lds16(gAnH + go0, sm + AnH + lo0);
            gload_lds16(gAnH + go1, sm + AnH + lo1);
            gload_lds16(gAnL + go0, sm + AnL + lo0);
            gload_lds16(gAnL + go1, sm + AnL + lo1);
            gload_lds16(gM0H + go0, sm + AmH + lo0);
            gload_lds16(gM0H + go1, sm + AmH + lo1);
            gload_lds16(gM1H + go0, sm + AmH + 4096 + lo0);
            gload_lds16(gM1H + go1, sm + AmH + 4096 + lo1);
            gload_lds16(gM0L + go0, sm + AmL + lo0);
            gload_lds16(gM0L + go1, sm + AmL + lo1);
            gload_lds16(gM1L + go0, sm + AmL + 4096 + lo0);
            gload_lds16(gM1L + go1, sm + AmL + 4096 + lo1);
        }
        __syncthreads();
        #pragma unroll
        for (int h = 0; h < 2; ++h) {
            short8 amh[2], aml[2];
            #pragma unroll
            for (int mi = 0; mi < 2; ++mi) {
                amh[mi] = ldfrag(sm + AmH + aoff[mi][h]);
                aml[mi] = ldfrag(sm + AmL + aoff[mi][h]);
            }
            #pragma unroll
            for (int ni = 0; ni < 4; ++ni) {
                const short8 bh = ldfrag(sm + AnH + boff[ni][h]);
                const short8 bl = ldfrag(sm + AnL + boff[ni][h]);
                #pragma unroll
                for (int mi = 0; mi < 2; ++mi) {
                    acc[mi][ni] = MFMA(amh[mi], bh, acc[mi][ni], 0, 0, 0);
                    acc[mi][ni] = MFMA(amh[mi], bl, acc[mi][ni], 0, 0, 0);
                    acc[mi][ni] = MFMA(aml[mi], bh, acc[mi][ni], 0, 0, 0);
                }
            }
        }
    }

    unsigned short* wsi = (unsigned short*)(ws + CANDI_OFF);

    // ---- n-side fold: per-lane top-3 over this tile's 256 cols ----
    const int mbase = mp * 256 + w * 64 + kh2 * 4;
    #pragma unroll
    for (int ni = 0; ni < 4; ++ni)
        #pragma unroll
        for (int mi = 0; mi < 2; ++mi)
            #pragma unroll
            for (int v = 0; v < 16; ++v) {
                const int m = mbase + mi * 32 + (v & 3) + 8 * (v >> 2);
                insert_cmp(acc[mi][ni][v], m,
                           t0v[ni], t0i[ni], t1v[ni], t1i[ni], t2v[ni], t2i[ni]);
            }

    // ---- m-side (mirrored) fold: only if mp > nt>>1 (dup-free rule) ----
    if (mp > (nt >> 1)) {
        #pragma unroll
        for (int mi = 0; mi < 2; ++mi) {
            #pragma unroll
            for (int v = 0; v < 16; ++v) {
                float q0 = -INFINITY, q1 = -INFINITY, q2 = -INFINITY;
                int j0 = BIGI, j1 = BIGI, j2 = BIGI;
                #pragma unroll
                for (int ni = 0; ni < 4; ++ni)
                    insert_cmp(acc[mi][ni][v], nt * 128 + ni * 32 + l31,
                               q0, j0, q1, j1, q2, j2);
                #pragma unroll
                for (int o = 1; o < 32; o <<= 1) {
                    const float p0 = __shfl_xor(q0, o), p1 = __shfl_xor(q1, o), p2 = __shfl_xor(q2, o);
                    const int a0 = __shfl_xor(j0, o), a1 = __shfl_xor(j1, o), a2 = __shfl_xor(j2, o);
                    insert_cmp(p0, a0, q0, j0, q1, j1, q2, j2);
                    insert_cmp(p1, a1, q0, j0, q1, j1, q2, j2);
                    insert_cmp(p2, a2, q0, j0, q1, j1, q2, j2);
                }
                if (l31 == 0) {
                    const int m = mbase + mi * 32 + (v & 3) + 8 * (v >> 2);  // global row
                    const size_t lb = (size_t)list_base(b, m) + (16 - mp + nt);
                    const size_t off = lb * 3;
                    ws[CANDV_OFF + off] = q0; ws[CANDV_OFF + off + 1] = q1; ws[CANDV_OFF + off + 2] = q2;
                    wsi[off] = (unsigned short)j0; wsi[off + 1] = (unsigned short)j1; wsi[off + 2] = (unsigned short)j2;
                }
            }
        }
    }

    // ---- n-side merge across kh2 halves + waves -> one list per row ----
    #pragma unroll
    for (int ni = 0; ni < 4; ++ni) {
        const float pv0 = __shfl_xor(t0v[ni], 32);
        const float pv1 = __shfl_xor(t1v[ni], 32);
        const float pv2 = __shfl_xor(t2v[ni], 32);
        const int pi0 = __shfl_xor(t0i[ni], 32);
        const int pi1 = __shfl_xor(t1i[ni], 32);
        const int pi2 = __shfl_xor(t2i[ni], 32);
        insert_cmp(pv0, pi0, t0v[ni], t0i[ni], t1v[ni], t1i[ni], t2v[ni], t2i[ni]);
        insert_cmp(pv1, pi1, t0v[ni], t0i[ni], t1v[ni], t1i[ni], t2v[ni], t2i[ni]);
        insert_cmp(pv2, pi2, t0v[ni], t0i[ni], t1v[ni], t1i[ni], t2v[ni], t2i[ni]);
    }
    __syncthreads();
    float* cv = (float*)sm;              // [w4][ni4][l32][3] floats
    int*   ci = (int*)sm + 1536;
    if (kh2 == 0) {
        #pragma unroll
        for (int ni = 0; ni < 4; ++ni) {
            const int base = ((w * 4 + ni) * 32 + l31) * 3;
            cv[base] = t0v[ni]; cv[base + 1] = t1v[ni]; cv[base + 2] = t2v[ni];
            ci[base] = t0i[ni]; ci[base + 1] = t1i[ni]; ci[base + 2] = t2i[ni];
        }
    }
    __syncthreads();
    if (tid < 128) {
        const int ni = tid >> 5, l = tid & 31;
        float v0 = -INFINITY, v1 = -INFINITY, v2 = -INFINITY;
        int i0 = BIGI, i1 = BIGI, i2 = BIGI;
        #pragma unroll
        for (int w2 = 0; w2 < 4; ++w2) {
            const int base = ((w2 * 4 + ni) * 32 + l) * 3;
            #pragma unroll
            for (int j = 0; j < 3; ++j)
                insert_cmp(cv[base + j], ci[base + j], v0, i0, v1, i1, v2, i2);
        }
        const int n_glob = nt * 128 + ni * 32 + l;
        const size_t lb = (size_t)list_base(b, n_glob) + (mp - (nt >> 1));
        const size_t o = lb * 3;
        ws[CANDV_OFF + o] = v0; ws[CANDV_OFF + o + 1] = v1; ws[CANDV_OFF + o + 2] = v2;
        wsi[o] = (unsigned short)i0; wsi[o + 1] = (unsigned short)i1; wsi[o + 2] = (unsigned short)i2;
    }
}

// Kernel 4: merge packed candidate lists -> global top-3; 27-way attention.
__global__ __launch_bounds__(256) void attn_kernel(const float* __restrict__ x,
                                                   const float* __restrict__ ws,
                                                   float* __restrict__ out) {
    const int wid = threadIdx.x >> 6;
    const int lane = threadIdx.x & 63;
    const int gw = blockIdx.x * 4 + wid;   // 0..16383
    const int b = gw >> 12;
    const int n = gw & 4095;

    float v0 = -INFINITY, v1 = -INFINITY, v2 = -INFINITY;
    int i0 = BIGI, i1 = BIGI, i2 = BIGI;
    const unsigned short* wi = (const unsigned short*)(ws + CANDI_OFF);
    const int cnt = 16 + (n >> 8);
    const size_t base = (size_t)list_base(b, n);
    for (int j = 0; j < cnt; ++j) {
        const size_t o = (base + j) * 3;
        #pragma unroll
        for (int u = 0; u < 3; ++u)
            insert_cmp(ws[CANDV_OFF + o + u], (int)wi[o + u], v0, i0, v1, i1, v2, i2);
    }
    const int idx3[3] = {i0, i1, i2};

    // per-lane feature meta for d = a*64 + lane  (torch reshape: K[...,a,c'] = xu[a*64+c'])
    int cc[9], dhh[9], dww[9];
    float inr[9];
    #pragma unroll
    for (int a = 0; a < 9; ++a) {
        const int d = a * 64 + lane;
        const int c = d / 9;
        const int p = d - c * 9;
        cc[a] = c; dhh[a] = p / 3 - 1; dww[a] = p - (p / 3) * 3 - 1;
        inr[a] = ws[INVN_OFF + b * ND + d];
    }
    const float q = x[((size_t)(b * 64 + lane) << 12) + n];

    float rv[27], sc[27];
    #pragma unroll
    for (int k = 0; k < 3; ++k) {
        const int m = idx3[k];
        const int hm = m >> 6, wm = m & 63;
        #pragma unroll
        for (int a = 0; a < 9; ++a) {
            const int r = hm + dhh[a], s2 = wm + dww[a];
            float val = 0.f;
            if ((unsigned)r < 64u && (unsigned)s2 < 64u)
                val = x[((size_t)(b * 64 + cc[a]) << 12) + (r << 6) + s2];
            const float rr = val * inr[a];
            rv[k * 9 + a] = rr;
            float t = q * rr;
            #pragma unroll
            for (int o2 = 32; o2 > 0; o2 >>= 1) t += __shfl_xor(t, o2);
            sc[k * 9 + a] = t * 0.125f;   // / sqrt(64)
        }
    }
    float mx = -INFINITY;
    #pragma unroll
    for (int u = 0; u < 27; ++u) mx = fmaxf(mx, sc[u]);
    float sum = 0.f;
    #pragma unroll
    for (int u = 0; u < 27; ++u) { const float e = expf(sc[u] - mx); sc[u] = e; sum += e; }
    const float inv = 1.0f / sum;
    float o = 0.f;
    #pragma unroll
    for (int u = 0; u < 27; ++u) o += sc[u] * rv[u];
    out[((size_t)gw << 6) + lane] = o * inv;
}

extern "C" void kernel_launch(void* const* d_in, const int* in_sizes, int n_in,
                              void* d_out, int out_size, void* d_ws, size_t ws_size,
                              hipStream_t stream) {
    (void)in_sizes; (void)n_in; (void)out_size; (void)ws_size;
    const float* x = (const float*)d_in[0];
    float* ws = (float*)d_ws;
    float* out = (float*)d_out;

    hipLaunchKernelGGL(norm_kernel, dim3(NB * 64), dim3(64), 0, stream, x, ws);
    hipLaunchKernelGGL(mat_kernel, dim3(2304), dim3(256), 0, stream, x, ws);
    hipLaunchKernelGGL(gram_kernel, dim3(1088), dim3(256), 0, stream, ws);
    hipLaunchKernelGGL(attn_kernel, dim3(4096), dim3(256), 0, stream, x, ws, out);
}

// Round 8
// 811.595 us; speedup vs baseline: 1.4827x; 1.4827x over previous
//
#include <hip/hip_runtime.h>
#include <cstdint>

typedef short short8 __attribute__((ext_vector_type(8)));
typedef float f32x16 __attribute__((ext_vector_type(16)));

// Problem constants
#define NB 4
#define NN 4096
#define ND 576
#define BIGI 0x7FFFFFFF
#define NSLICE 16

// ws layout: A_hi (bf16) [b][tile32][kc18][512 chunks of 16B] = 9437184 shorts,
// then A_lo same size; then (float units):
#define INVN_OFF 9437184
#define CANDV_OFF 9439488
// CANDV: 4*16*4096*3 = 786432 floats -> ends at 10225920
#define CANDI_OFF 10225920
// CANDI: 786432 u16 = 393216 float-equiv -> total 10619136 floats = 42.5 MB
// (<= 44.7 MB proven in round 7)
// Chunk swizzle (baked into layout): chunk g = r*4 + c', source chunk
// c = c' ^ ((r>>1)&3).

#define MFMA __builtin_amdgcn_mfma_f32_32x32x16_bf16

__device__ __forceinline__ unsigned short f2bf(float f) {
    unsigned u = __float_as_uint(f);
    u += 0x7FFFu + ((u >> 16) & 1u);   // round-to-nearest-even
    return (unsigned short)(u >> 16);
}

__device__ __forceinline__ void gload_lds16(const void* g, void* l) {
    __builtin_amdgcn_global_load_lds(
        (const __attribute__((address_space(1))) void*)g,
        (__attribute__((address_space(3))) void*)l, 16, 0, 0);
}

// Exact jax top_k comparator: bigger value wins; tie -> smaller index wins.
__device__ __forceinline__ void insert_cmp(float v, int m,
    float& v0, int& i0, float& v1, int& i1, float& v2, int& i2) {
    bool beat2 = (v > v2) || (v == v2 && m < i2);
    if (beat2) {
        bool beat1 = (v > v1) || (v == v1 && m < i1);
        if (beat1) {
            v2 = v1; i2 = i1;
            bool beat0 = (v > v0) || (v == v0 && m < i0);
            if (beat0) { v1 = v0; i1 = i0; v0 = v; i0 = m; }
            else       { v1 = v;  i1 = m; }
        } else { v2 = v; i2 = m; }
    }
}

// Kernel 1: per-(b,c) windowed sums of x^2 -> inv norms for the 9 kernel offsets.
__global__ __launch_bounds__(64) void norm_kernel(const float* __restrict__ x,
                                                  float* __restrict__ ws) {
    const int bc = blockIdx.x;          // b*64 + c
    const int lane = threadIdx.x;       // = column w
    const float* xp = x + ((size_t)bc << 12);
    float colsum = 0.f, v0 = 0.f, v63 = 0.f;
    for (int h = 0; h < 64; ++h) {
        const float val = xp[(h << 6) + lane];
        const float sq = val * val;
        colsum += sq;
        if (h == 0)  v0 = sq;
        if (h == 63) v63 = sq;
    }
    float total = colsum, row0 = v0, row63 = v63;
    #pragma unroll
    for (int o = 32; o > 0; o >>= 1) {
        total += __shfl_xor(total, o);
        row0  += __shfl_xor(row0, o);
        row63 += __shfl_xor(row63, o);
    }
    const float col0  = __shfl(colsum, 0);
    const float col63 = __shfl(colsum, 63);
    const float c00 = __shfl(v0, 0),  c0e = __shfl(v0, 63);
    const float ce0 = __shfl(v63, 0), cee = __shfl(v63, 63);
    if (lane < 9) {
        const int dh = lane / 3 - 1, dw = lane % 3 - 1;
        float S = total;
        if (dh == 1)  S -= row0;
        if (dh == -1) S -= row63;
        if (dw == 1)  S -= col0;
        if (dw == -1) S -= col63;
        if (dh == 1  && dw == 1)  S += c00;
        if (dh == 1  && dw == -1) S += c0e;
        if (dh == -1 && dw == 1)  S += ce0;
        if (dh == -1 && dw == -1) S += cee;
        float nrm = fmaxf(sqrtf(S), 1e-12f);
        ws[INVN_OFF + bc * 9 + lane] = 1.0f / nrm;
    }
}

// Kernel 2: split-bf16 materialization with baked chunk swizzle.
// blockIdx = (b*32+nt)*18+kc. Region = 512 chunks of 16B (8 bf16).
__global__ __launch_bounds__(256) void mat_kernel(const float* __restrict__ x,
                                                  float* __restrict__ ws) {
    const int bi = blockIdx.x;             // 2304 blocks
    const int b = bi / 576;
    const int rem = bi - b * 576;
    const int nt = rem / 18;
    const int kc = rem - nt * 18;
    unsigned short* AH = (unsigned short*)ws;
    unsigned short* AL = AH + 9437184;
    const float* invn = ws + INVN_OFF + b * 576;
    const int tid = threadIdx.x;
    #pragma unroll
    for (int hf2 = 0; hf2 < 2; ++hf2) {
        const int g = tid + hf2 * 256;     // output chunk 0..511
        const int row = g >> 2, cp = g & 3;
        const int c = cp ^ ((row >> 1) & 3);    // source chunk (swizzle)
        const int k0 = c * 8;
        const int n = nt * 128 + row;
        const int h = n >> 6, wc = n & 63;
        union { unsigned short us[8]; float4 f4; } uh, ul;
        #pragma unroll
        for (int j = 0; j < 8; ++j) {
            const int d = kc * 32 + k0 + j;
            const int ch = d / 9;
            const int p = d - ch * 9;
            const int r = h + p / 3 - 1, s2 = wc + p % 3 - 1;
            float val = 0.f;
            if ((unsigned)r < 64u && (unsigned)s2 < 64u)
                val = x[((size_t)(b * 64 + ch) << 12) + (r << 6) + s2];
            val *= invn[d];
            const unsigned short hb = f2bf(val);
            const float hfv = __uint_as_float(((unsigned)hb) << 16);
            const unsigned short lb = f2bf(val - hfv);
            uh.us[j] = hb; ul.us[j] = lb;
        }
        ((float4*)AH)[(size_t)bi * 512 + g] = uh.f4;
        ((float4*)AL)[(size_t)bi * 512 + g] = ul.f4;
    }
}

__device__ __forceinline__ short8 ldfrag(const short* p) {
    union { short8 s8; float4 f4; } u;
    u.f4 = *(const float4*)p;
    return u.s8;
}

// Kernel 3: R = A^T A via split-bf16 MFMA (hh + hl + lh), fused top-3.
// Grid 1024 = b(4) x 256 tiles; XCD-rect mapping: XCD x (=bx%8) covers
// I in [4*(x>>1),+4), J in [8*(x&1),+8). Block: 256n x 256m, 512 thr (8 waves),
// wave tile 128n x 64m (acc[2][4]). Double-buffered 2x64KB LDS; DMA issued one
// kc ahead, manual s_waitcnt vmcnt(8) + raw s_barrier (never a full drain).
// C/D: m_part = (reg&3)+8*(reg>>2)+4*(lane>>5), n_part = lane&31  [HW-verified r4]
__global__ void __launch_bounds__(512, 2) gram_kernel(float* ws) {
    __shared__ short sm[65536];   // 128KB = 2 buffers x (An 16K | AnL 16K | AmH 16K | AmL 16K)
    const int bx = blockIdx.x;
    const int b = bx >> 8;
    const int t = bx & 255;
    const int x = t & 7, g = t >> 3;
    const int I = (x >> 1) * 4 + (g >> 3);
    const int J = (x & 1) * 8 + (g & 7);
    const int tid = threadIdx.x;
    const int w = tid >> 6, lane = tid & 63;
    const int wn = w >> 2, wm = w & 3;
    const int l31 = lane & 31, kh2 = lane >> 5;

    const unsigned short* AH = (const unsigned short*)ws;
    const unsigned short* AL = AH + 9437184;

    // staging: wave w owns region w: w0,1=AnH(2I,2I+1) w2,3=AnL w4,5=AmH(2J,2J+1) w6,7=AmL
    const unsigned short* gplane = (((w >> 1) & 1) == 0) ? AH : AL;
    const int gtile = (w < 4) ? (2 * I + (w & 1)) : (2 * J + (w & 1));
    const unsigned short* gbase = gplane + (size_t)((b * 32 + gtile) * 18) * 4096;
    const int ldsReg = w * 4096;         // shorts, within one 32768-short buffer

    // frag offsets (shorts, region-local row in [0,128)): row*32 + (c^((row>>1)&3))*8
    int aoff[2][2];      // [mi][h] within AmH/AmL area (incl region select)
    int boff[4][2];      // [ni][h] within AnH/AnL area
    #pragma unroll
    for (int mi = 0; mi < 2; ++mi)
        #pragma unroll
        for (int h = 0; h < 2; ++h) {
            const int row = (wm & 1) * 64 + mi * 32 + l31;
            const int c = kh2 + 2 * h;
            aoff[mi][h] = (wm >> 1) * 4096 + row * 32 + (c ^ ((row >> 1) & 3)) * 8;
        }
    #pragma unroll
    for (int ni = 0; ni < 4; ++ni)
        #pragma unroll
        for (int h = 0; h < 2; ++h) {
            const int row = ni * 32 + l31;
            const int c = kh2 + 2 * h;
            boff[ni][h] = wn * 4096 + row * 32 + (c ^ ((row >> 1) & 3)) * 8;
        }

    f32x16 acc[2][4];
    #pragma unroll
    for (int mi = 0; mi < 2; ++mi)
        #pragma unroll
        for (int ni = 0; ni < 4; ++ni)
            #pragma unroll
            for (int e = 0; e < 16; ++e) acc[mi][ni][e] = 0.f;

    // prologue: stage kc=0 into buffer 0
    {
        const unsigned short* gs = gbase;
        short* dst = sm + ldsReg;
        #pragma unroll
        for (int i = 0; i < 8; ++i)
            gload_lds16(gs + i * 512 + lane * 8, dst + i * 512 + lane * 8);
    }

    for (int kc = 0; kc < 18; ++kc) {
        if (kc < 17) {
            const unsigned short* gs = gbase + (size_t)(kc + 1) * 4096;
            short* dst = sm + ((kc + 1) & 1) * 32768 + ldsReg;
            #pragma unroll
            for (int i = 0; i < 8; ++i)
                gload_lds16(gs + i * 512 + lane * 8, dst + i * 512 + lane * 8);
            asm volatile("s_waitcnt vmcnt(8)" ::: "memory");
        } else {
            asm volatile("s_waitcnt vmcnt(0)" ::: "memory");
        }
        asm volatile("s_barrier" ::: "memory");
        const short* base = sm + (kc & 1) * 32768;
        #pragma unroll
        for (int h = 0; h < 2; ++h) {
            short8 amh[2], aml[2];
            #pragma unroll
            for (int mi = 0; mi < 2; ++mi) {
                amh[mi] = ldfrag(base + 16384 + aoff[mi][h]);
                aml[mi] = ldfrag(base + 24576 + aoff[mi][h]);
            }
            #pragma unroll
            for (int ni = 0; ni < 4; ++ni) {
                const short8 bh = ldfrag(base + boff[ni][h]);
                const short8 bl = ldfrag(base + 8192 + boff[ni][h]);
                #pragma unroll
                for (int mi = 0; mi < 2; ++mi) {
                    acc[mi][ni] = MFMA(amh[mi], bh, acc[mi][ni], 0, 0, 0);
                    acc[mi][ni] = MFMA(amh[mi], bl, acc[mi][ni], 0, 0, 0);
                    acc[mi][ni] = MFMA(aml[mi], bh, acc[mi][ni], 0, 0, 0);
                }
            }
        }
        asm volatile("s_barrier" ::: "memory");   // protect buffer reuse
    }

    // fold acc into per-lane top-3 (per ni; row n = (2I+wn)*128 + ni*32 + l31)
    float t0v[4], t1v[4], t2v[4];
    int   t0i[4], t1i[4], t2i[4];
    #pragma unroll
    for (int i = 0; i < 4; ++i) {
        t0v[i] = t1v[i] = t2v[i] = -INFINITY;
        t0i[i] = t1i[i] = t2i[i] = BIGI;
    }
    const int mbase = J * 256 + wm * 64 + kh2 * 4;
    #pragma unroll
    for (int ni = 0; ni < 4; ++ni)
        #pragma unroll
        for (int mi = 0; mi < 2; ++mi)
            #pragma unroll
            for (int v = 0; v < 16; ++v) {
                const int m = mbase + mi * 32 + (v & 3) + 8 * (v >> 2);
                insert_cmp(acc[mi][ni][v], m,
                           t0v[ni], t0i[ni], t1v[ni], t1i[ni], t2v[ni], t2i[ni]);
            }

    // merge the two kh2 halves (same n, disjoint m) via shfl
    #pragma unroll
    for (int ni = 0; ni < 4; ++ni) {
        const float pv0 = __shfl_xor(t0v[ni], 32);
        const float pv1 = __shfl_xor(t1v[ni], 32);
        const float pv2 = __shfl_xor(t2v[ni], 32);
        const int pi0 = __shfl_xor(t0i[ni], 32);
        const int pi1 = __shfl_xor(t1i[ni], 32);
        const int pi2 = __shfl_xor(t2i[ni], 32);
        insert_cmp(pv0, pi0, t0v[ni], t0i[ni], t1v[ni], t1i[ni], t2v[ni], t2i[ni]);
        insert_cmp(pv1, pi1, t0v[ni], t0i[ni], t1v[ni], t1i[ni], t2v[ni], t2i[ni]);
        insert_cmp(pv2, pi2, t0v[ni], t0i[ni], t1v[ni], t1i[ni], t2v[ni], t2i[ni]);
    }
    // cross-wave merge: rows (wn) merged across the 4 wm waves
    __syncthreads();
    float* cv = (float*)sm;              // [w8][ni4][l32][3] floats
    int*   ci = (int*)sm + 3072;
    if (kh2 == 0) {
        #pragma unroll
        for (int ni = 0; ni < 4; ++ni) {
            const int base2 = ((w * 4 + ni) * 32 + l31) * 3;
            cv[base2] = t0v[ni]; cv[base2 + 1] = t1v[ni]; cv[base2 + 2] = t2v[ni];
            ci[base2] = t0i[ni]; ci[base2 + 1] = t1i[ni]; ci[base2 + 2] = t2i[ni];
        }
    }
    __syncthreads();
    if (tid < 256) {
        const int wnr = tid >> 7, rl = tid & 127;
        const int ni = rl >> 5, l = rl & 31;
        float v0 = -INFINITY, v1 = -INFINITY, v2 = -INFINITY;
        int i0 = BIGI, i1 = BIGI, i2 = BIGI;
        #pragma unroll
        for (int wm2 = 0; wm2 < 4; ++wm2) {
            const int base2 = (((wnr * 4 + wm2) * 4 + ni) * 32 + l) * 3;
            #pragma unroll
            for (int j = 0; j < 3; ++j)
                insert_cmp(cv[base2 + j], ci[base2 + j], v0, i0, v1, i1, v2, i2);
        }
        const int n_glob = (2 * I + wnr) * 128 + ni * 32 + l;
        const size_t o = ((size_t)(b * NSLICE + J) * NN + n_glob) * 3;
        ws[CANDV_OFF + o] = v0; ws[CANDV_OFF + o + 1] = v1; ws[CANDV_OFF + o + 2] = v2;
        unsigned short* wi = (unsigned short*)(ws + CANDI_OFF);
        wi[o] = (unsigned short)i0; wi[o + 1] = (unsigned short)i1; wi[o + 2] = (unsigned short)i2;
    }
}

// Kernel 4: merge slice candidates -> global top-3; 27-way attention. One wave per n.
__global__ __launch_bounds__(256) void attn_kernel(const float* __restrict__ x,
                                                   const float* __restrict__ ws,
                                                   float* __restrict__ out) {
    const int wid = threadIdx.x >> 6;
    const int lane = threadIdx.x & 63;
    const int gw = blockIdx.x * 4 + wid;   // 0..16383
    const int b = gw >> 12;
    const int n = gw & 4095;

    float v0 = -INFINITY, v1 = -INFINITY, v2 = -INFINITY;
    int i0 = BIGI, i1 = BIGI, i2 = BIGI;
    const unsigned short* wi = (const unsigned short*)(ws + CANDI_OFF);
    for (int s = 0; s < NSLICE; ++s) {
        const size_t o = ((size_t)(b * NSLICE + s) * NN + n) * 3;
        #pragma unroll
        for (int j = 0; j < 3; ++j)
            insert_cmp(ws[CANDV_OFF + o + j], (int)wi[o + j], v0, i0, v1, i1, v2, i2);
    }
    const int idx3[3] = {i0, i1, i2};

    // per-lane feature meta for d = a*64 + lane  (torch reshape: K[...,a,c'] = xu[a*64+c'])
    int cc[9], dhh[9], dww[9];
    float inr[9];
    #pragma unroll
    for (int a = 0; a < 9; ++a) {
        const int d = a * 64 + lane;
        const int c = d / 9;
        const int p = d - c * 9;
        cc[a] = c; dhh[a] = p / 3 - 1; dww[a] = p - (p / 3) * 3 - 1;
        inr[a] = ws[INVN_OFF + b * ND + d];
    }
    const float q = x[((size_t)(b * 64 + lane) << 12) + n];

    float rv[27], sc[27];
    #pragma unroll
    for (int k = 0; k < 3; ++k) {
        const int m = idx3[k];
        const int hm = m >> 6, wm = m & 63;
        #pragma unroll
        for (int a = 0; a < 9; ++a) {
            const int r = hm + dhh[a], s2 = wm + dww[a];
            float val = 0.f;
            if ((unsigned)r < 64u && (unsigned)s2 < 64u)
                val = x[((size_t)(b * 64 + cc[a]) << 12) + (r << 6) + s2];
            const float rr = val * inr[a];
            rv[k * 9 + a] = rr;
            float t = q * rr;
            #pragma unroll
            for (int o2 = 32; o2 > 0; o2 >>= 1) t += __shfl_xor(t, o2);
            sc[k * 9 + a] = t * 0.125f;   // / sqrt(64)
        }
    }
    float mx = -INFINITY;
    #pragma unroll
    for (int u = 0; u < 27; ++u) mx = fmaxf(mx, sc[u]);
    float sum = 0.f;
    #pragma unroll
    for (int u = 0; u < 27; ++u) { const float e = expf(sc[u] - mx); sc[u] = e; sum += e; }
    const float inv = 1.0f / sum;
    float o = 0.f;
    #pragma unroll
    for (int u = 0; u < 27; ++u) o += sc[u] * rv[u];
    out[((size_t)gw << 6) + lane] = o * inv;
}

extern "C" void kernel_launch(void* const* d_in, const int* in_sizes, int n_in,
                              void* d_out, int out_size, void* d_ws, size_t ws_size,
                              hipStream_t stream) {
    (void)in_sizes; (void)n_in; (void)out_size; (void)ws_size;
    const float* x = (const float*)d_in[0];
    float* ws = (float*)d_ws;
    float* out = (float*)d_out;

    hipLaunchKernelGGL(norm_kernel, dim3(NB * 64), dim3(64), 0, stream, x, ws);
    hipLaunchKernelGGL(mat_kernel, dim3(2304), dim3(256), 0, stream, x, ws);
    hipLaunchKernelGGL(gram_kernel, dim3(1024), dim3(512), 0, stream, ws);
    hipLaunchKernelGGL(attn_kernel, dim3(4096), dim3(256), 0, stream, x, ws, out);
}

// Round 9
// 808.269 us; speedup vs baseline: 1.4888x; 1.0041x over previous
//
#include <hip/hip_runtime.h>
#include <cstdint>

typedef short short8 __attribute__((ext_vector_type(8)));
typedef float f32x16 __attribute__((ext_vector_type(16)));

// Problem constants
#define NB 4
#define NN 4096
#define ND 576
#define BIGI 0x7FFFFFFF
#define NSLICE 16

// ws layout: A_hi (bf16) [b][tile32][kc18][512 chunks of 16B] = 9437184 shorts,
// then A_lo same size; then (float units):
#define INVN_OFF 9437184
#define CANDV_OFF 9439488
// CANDV: 4*16*4096*3 = 786432 floats -> ends at 10225920
#define CANDI_OFF 10225920
// CANDI: 786432 u16 = 393216 float-equiv -> total 10619136 floats = 42.5 MB (proven r8)
// Chunk swizzle (baked into layout): chunk g = r*4 + c', source chunk c = c' ^ ((r>>1)&3).

#define MFMA __builtin_amdgcn_mfma_f32_32x32x16_bf16

__device__ __forceinline__ unsigned short f2bf(float f) {
    unsigned u = __float_as_uint(f);
    u += 0x7FFFu + ((u >> 16) & 1u);   // round-to-nearest-even
    return (unsigned short)(u >> 16);
}

// Exact jax top_k comparator: bigger value wins; tie -> smaller index wins.
__device__ __forceinline__ void insert_cmp(float v, int m,
    float& v0, int& i0, float& v1, int& i1, float& v2, int& i2) {
    bool beat2 = (v > v2) || (v == v2 && m < i2);
    if (beat2) {
        bool beat1 = (v > v1) || (v == v1 && m < i1);
        if (beat1) {
            v2 = v1; i2 = i1;
            bool beat0 = (v > v0) || (v == v0 && m < i0);
            if (beat0) { v1 = v0; i1 = i0; v0 = v; i0 = m; }
            else       { v1 = v;  i1 = m; }
        } else { v2 = v; i2 = m; }
    }
}

// Kernel 1: per-(b,c) windowed sums of x^2 -> inv norms for the 9 kernel offsets.
__global__ __launch_bounds__(64) void norm_kernel(const float* __restrict__ x,
                                                  float* __restrict__ ws) {
    const int bc = blockIdx.x;          // b*64 + c
    const int lane = threadIdx.x;       // = column w
    const float* xp = x + ((size_t)bc << 12);
    float colsum = 0.f, v0 = 0.f, v63 = 0.f;
    for (int h = 0; h < 64; ++h) {
        const float val = xp[(h << 6) + lane];
        const float sq = val * val;
        colsum += sq;
        if (h == 0)  v0 = sq;
        if (h == 63) v63 = sq;
    }
    float total = colsum, row0 = v0, row63 = v63;
    #pragma unroll
    for (int o = 32; o > 0; o >>= 1) {
        total += __shfl_xor(total, o);
        row0  += __shfl_xor(row0, o);
        row63 += __shfl_xor(row63, o);
    }
    const float col0  = __shfl(colsum, 0);
    const float col63 = __shfl(colsum, 63);
    const float c00 = __shfl(v0, 0),  c0e = __shfl(v0, 63);
    const float ce0 = __shfl(v63, 0), cee = __shfl(v63, 63);
    if (lane < 9) {
        const int dh = lane / 3 - 1, dw = lane % 3 - 1;
        float S = total;
        if (dh == 1)  S -= row0;
        if (dh == -1) S -= row63;
        if (dw == 1)  S -= col0;
        if (dw == -1) S -= col63;
        if (dh == 1  && dw == 1)  S += c00;
        if (dh == 1  && dw == -1) S += c0e;
        if (dh == -1 && dw == 1)  S += ce0;
        if (dh == -1 && dw == -1) S += cee;
        float nrm = fmaxf(sqrtf(S), 1e-12f);
        ws[INVN_OFF + bc * 9 + lane] = 1.0f / nrm;
    }
}

// Kernel 2: split-bf16 materialization with baked chunk swizzle.
// blockIdx = (b*32+nt)*18+kc. Region = 512 chunks of 16B (8 bf16).
__global__ __launch_bounds__(256) void mat_kernel(const float* __restrict__ x,
                                                  float* __restrict__ ws) {
    const int bi = blockIdx.x;             // 2304 blocks
    const int b = bi / 576;
    const int rem = bi - b * 576;
    const int nt = rem / 18;
    const int kc = rem - nt * 18;
    unsigned short* AH = (unsigned short*)ws;
    unsigned short* AL = AH + 9437184;
    const float* invn = ws + INVN_OFF + b * 576;
    const int tid = threadIdx.x;
    #pragma unroll
    for (int hf2 = 0; hf2 < 2; ++hf2) {
        const int g = tid + hf2 * 256;     // output chunk 0..511
        const int row = g >> 2, cp = g & 3;
        const int c = cp ^ ((row >> 1) & 3);    // source chunk (swizzle)
        const int k0 = c * 8;
        const int n = nt * 128 + row;
        const int h = n >> 6, wc = n & 63;
        union { unsigned short us[8]; float4 f4; } uh, ul;
        #pragma unroll
        for (int j = 0; j < 8; ++j) {
            const int d = kc * 32 + k0 + j;
            const int ch = d / 9;
            const int p = d - ch * 9;
            const int r = h + p / 3 - 1, s2 = wc + p % 3 - 1;
            float val = 0.f;
            if ((unsigned)r < 64u && (unsigned)s2 < 64u)
                val = x[((size_t)(b * 64 + ch) << 12) + (r << 6) + s2];
            val *= invn[d];
            const unsigned short hb = f2bf(val);
            const float hfv = __uint_as_float(((unsigned)hb) << 16);
            const unsigned short lb = f2bf(val - hfv);
            uh.us[j] = hb; ul.us[j] = lb;
        }
        ((float4*)AH)[(size_t)bi * 512 + g] = uh.f4;
        ((float4*)AL)[(size_t)bi * 512 + g] = ul.f4;
    }
}

__device__ __forceinline__ short8 ldfragG(const unsigned short* p) {
    union { short8 s8; float4 f4; } u;
    u.f4 = *(const float4*)p;
    return u.s8;
}

// Kernel 3: R = A^T A via split-bf16 MFMA (hh + hl + lh), fused top-3.
// ZERO-LDS K-loop: both operands read directly from global (L2/LLC-resident,
// fragment-contiguous layout -> 1 dwordx4 per frag), no barriers -> every wave
// is an independent load+MFMA stream; compiler vmcnt pipelining hides latency.
// Grid 2048 = 8 rounds x 256; XCD-rect: x=t&7 covers nt-rect 4 x ms-rect 8.
// Block: 128n x 256m, 4 waves, wave tile 128n x 64m (acc[2][4]).
// C/D: m_part = (reg&3)+8*(reg>>2)+4*(lane>>5), n_part = lane&31  [HW-verified r4]
__global__ void __launch_bounds__(256, 2) gram_kernel(float* ws) {
    __shared__ float cv[1536];
    __shared__ int   ci[1536];
    const int bx = blockIdx.x;
    const int r = bx >> 8;               // round 0..7
    const int t = bx & 255;
    const int x = t & 7, g = t >> 3;
    const int b = r >> 1;
    const int half = r & 1;
    const int nt = 16 * half + 4 * (x >> 1) + (g >> 3);   // 0..31
    const int ms = 8 * (x & 1) + (g & 7);                 // 0..15 (256-col slice)
    const int tid = threadIdx.x;
    const int w = tid >> 6, lane = tid & 63;
    const int l31 = lane & 31, kh2 = lane >> 5;

    const unsigned short* AH = (const unsigned short*)ws;
    const unsigned short* AL = AH + 9437184;

    // global bases (shorts)
    const unsigned short* gAn[2] = {
        AH + (size_t)((b * 32 + nt) * 18) * 4096,
        AL + (size_t)((b * 32 + nt) * 18) * 4096 };
    const unsigned short* gAm[2][2];     // [mi][plane]
    #pragma unroll
    for (int mi = 0; mi < 2; ++mi) {
        const int tile = 2 * ms + ((2 * w + mi) >> 2);
        gAm[mi][0] = AH + (size_t)((b * 32 + tile) * 18) * 4096;
        gAm[mi][1] = AL + (size_t)((b * 32 + tile) * 18) * 4096;
    }

    // frag offsets (shorts, excl. kc*4096): row*32 + (c^((row>>1)&3))*8, c=kh2+2h
    int boff[4][2], aoff[2][2];
    #pragma unroll
    for (int ni = 0; ni < 4; ++ni)
        #pragma unroll
        for (int h = 0; h < 2; ++h) {
            const int row = ni * 32 + l31;
            const int c = kh2 + 2 * h;
            boff[ni][h] = row * 32 + (c ^ ((row >> 1) & 3)) * 8;
        }
    #pragma unroll
    for (int mi = 0; mi < 2; ++mi)
        #pragma unroll
        for (int h = 0; h < 2; ++h) {
            const int row = (w * 64 + mi * 32 + l31) & 127;
            const int c = kh2 + 2 * h;
            aoff[mi][h] = row * 32 + (c ^ ((row >> 1) & 3)) * 8;
        }

    f32x16 acc[2][4];
    #pragma unroll
    for (int mi = 0; mi < 2; ++mi)
        #pragma unroll
        for (int ni = 0; ni < 4; ++ni)
            #pragma unroll
            for (int e = 0; e < 16; ++e) acc[mi][ni][e] = 0.f;

    for (int kc = 0; kc < 18; ++kc) {
        const int kb = kc * 4096;
        #pragma unroll
        for (int h = 0; h < 2; ++h) {
            short8 amh[2], aml[2], bh[4], bl[4];
            #pragma unroll
            for (int mi = 0; mi < 2; ++mi) {
                amh[mi] = ldfragG(gAm[mi][0] + kb + aoff[mi][h]);
                aml[mi] = ldfragG(gAm[mi][1] + kb + aoff[mi][h]);
            }
            #pragma unroll
            for (int ni = 0; ni < 4; ++ni) {
                bh[ni] = ldfragG(gAn[0] + kb + boff[ni][h]);
                bl[ni] = ldfragG(gAn[1] + kb + boff[ni][h]);
            }
            #pragma unroll
            for (int ni = 0; ni < 4; ++ni)
                #pragma unroll
                for (int mi = 0; mi < 2; ++mi) {
                    acc[mi][ni] = MFMA(amh[mi], bh[ni], acc[mi][ni], 0, 0, 0);
                    acc[mi][ni] = MFMA(amh[mi], bl[ni], acc[mi][ni], 0, 0, 0);
                    acc[mi][ni] = MFMA(aml[mi], bh[ni], acc[mi][ni], 0, 0, 0);
                }
        }
    }

    // fold acc into per-lane top-3 (per ni; n = nt*128 + ni*32 + l31)
    float t0v[4], t1v[4], t2v[4];
    int   t0i[4], t1i[4], t2i[4];
    #pragma unroll
    for (int i = 0; i < 4; ++i) {
        t0v[i] = t1v[i] = t2v[i] = -INFINITY;
        t0i[i] = t1i[i] = t2i[i] = BIGI;
    }
    const int mbase = ms * 256 + w * 64 + kh2 * 4;
    #pragma unroll
    for (int ni = 0; ni < 4; ++ni)
        #pragma unroll
        for (int mi = 0; mi < 2; ++mi)
            #pragma unroll
            for (int v = 0; v < 16; ++v) {
                const int m = mbase + mi * 32 + (v & 3) + 8 * (v >> 2);
                insert_cmp(acc[mi][ni][v], m,
                           t0v[ni], t0i[ni], t1v[ni], t1i[ni], t2v[ni], t2i[ni]);
            }

    // merge the two kh2 halves (same n, disjoint m) via shfl
    #pragma unroll
    for (int ni = 0; ni < 4; ++ni) {
        const float pv0 = __shfl_xor(t0v[ni], 32);
        const float pv1 = __shfl_xor(t1v[ni], 32);
        const float pv2 = __shfl_xor(t2v[ni], 32);
        const int pi0 = __shfl_xor(t0i[ni], 32);
        const int pi1 = __shfl_xor(t1i[ni], 32);
        const int pi2 = __shfl_xor(t2i[ni], 32);
        insert_cmp(pv0, pi0, t0v[ni], t0i[ni], t1v[ni], t1i[ni], t2v[ni], t2i[ni]);
        insert_cmp(pv1, pi1, t0v[ni], t0i[ni], t1v[ni], t1i[ni], t2v[ni], t2i[ni]);
        insert_cmp(pv2, pi2, t0v[ni], t0i[ni], t1v[ni], t1i[ni], t2v[ni], t2i[ni]);
    }
    // cross-wave merge through LDS (each wave owns a 64-wide m slice)
    __syncthreads();
    if (kh2 == 0) {
        #pragma unroll
        for (int ni = 0; ni < 4; ++ni) {
            const int base2 = ((w * 4 + ni) * 32 + l31) * 3;
            cv[base2] = t0v[ni]; cv[base2 + 1] = t1v[ni]; cv[base2 + 2] = t2v[ni];
            ci[base2] = t0i[ni]; ci[base2 + 1] = t1i[ni]; ci[base2 + 2] = t2i[ni];
        }
    }
    __syncthreads();
    if (tid < 128) {
        const int ni = tid >> 5, l = tid & 31;
        float v0 = -INFINITY, v1 = -INFINITY, v2 = -INFINITY;
        int i0 = BIGI, i1 = BIGI, i2 = BIGI;
        #pragma unroll
        for (int w2 = 0; w2 < 4; ++w2) {
            const int base2 = ((w2 * 4 + ni) * 32 + l) * 3;
            #pragma unroll
            for (int j = 0; j < 3; ++j)
                insert_cmp(cv[base2 + j], ci[base2 + j], v0, i0, v1, i1, v2, i2);
        }
        const int n_glob = nt * 128 + ni * 32 + l;
        const size_t o = ((size_t)(b * NSLICE + ms) * NN + n_glob) * 3;
        ws[CANDV_OFF + o] = v0; ws[CANDV_OFF + o + 1] = v1; ws[CANDV_OFF + o + 2] = v2;
        unsigned short* wi = (unsigned short*)(ws + CANDI_OFF);
        wi[o] = (unsigned short)i0; wi[o + 1] = (unsigned short)i1; wi[o + 2] = (unsigned short)i2;
    }
}

// Kernel 4: merge slice candidates -> global top-3; 27-way attention. One wave per n.
__global__ __launch_bounds__(256) void attn_kernel(const float* __restrict__ x,
                                                   const float* __restrict__ ws,
                                                   float* __restrict__ out) {
    const int wid = threadIdx.x >> 6;
    const int lane = threadIdx.x & 63;
    const int gw = blockIdx.x * 4 + wid;   // 0..16383
    const int b = gw >> 12;
    const int n = gw & 4095;

    float v0 = -INFINITY, v1 = -INFINITY, v2 = -INFINITY;
    int i0 = BIGI, i1 = BIGI, i2 = BIGI;
    const unsigned short* wi = (const unsigned short*)(ws + CANDI_OFF);
    for (int s = 0; s < NSLICE; ++s) {
        const size_t o = ((size_t)(b * NSLICE + s) * NN + n) * 3;
        #pragma unroll
        for (int j = 0; j < 3; ++j)
            insert_cmp(ws[CANDV_OFF + o + j], (int)wi[o + j], v0, i0, v1, i1, v2, i2);
    }
    const int idx3[3] = {i0, i1, i2};

    // per-lane feature meta for d = a*64 + lane  (torch reshape: K[...,a,c'] = xu[a*64+c'])
    int cc[9], dhh[9], dww[9];
    float inr[9];
    #pragma unroll
    for (int a = 0; a < 9; ++a) {
        const int d = a * 64 + lane;
        const int c = d / 9;
        const int p = d - c * 9;
        cc[a] = c; dhh[a] = p / 3 - 1; dww[a] = p - (p / 3) * 3 - 1;
        inr[a] = ws[INVN_OFF + b * ND + d];
    }
    const float q = x[((size_t)(b * 64 + lane) << 12) + n];

    float rv[27], sc[27];
    #pragma unroll
    for (int k = 0; k < 3; ++k) {
        const int m = idx3[k];
        const int hm = m >> 6, wm = m & 63;
        #pragma unroll
        for (int a = 0; a < 9; ++a) {
            const int r = hm + dhh[a], s2 = wm + dww[a];
            float val = 0.f;
            if ((unsigned)r < 64u && (unsigned)s2 < 64u)
                val = x[((size_t)(b * 64 + cc[a]) << 12) + (r << 6) + s2];
            const float rr = val * inr[a];
            rv[k * 9 + a] = rr;
            float t = q * rr;
            #pragma unroll
            for (int o2 = 32; o2 > 0; o2 >>= 1) t += __shfl_xor(t, o2);
            sc[k * 9 + a] = t * 0.125f;   // / sqrt(64)
        }
    }
    float mx = -INFINITY;
    #pragma unroll
    for (int u = 0; u < 27; ++u) mx = fmaxf(mx, sc[u]);
    float sum = 0.f;
    #pragma unroll
    for (int u = 0; u < 27; ++u) { const float e = expf(sc[u] - mx); sc[u] = e; sum += e; }
    const float inv = 1.0f / sum;
    float o = 0.f;
    #pragma unroll
    for (int u = 0; u < 27; ++u) o += sc[u] * rv[u];
    out[((size_t)gw << 6) + lane] = o * inv;
}

extern "C" void kernel_launch(void* const* d_in, const int* in_sizes, int n_in,
                              void* d_out, int out_size, void* d_ws, size_t ws_size,
                              hipStream_t stream) {
    (void)in_sizes; (void)n_in; (void)out_size; (void)ws_size;
    const float* x = (const float*)d_in[0];
    float* ws = (float*)d_ws;
    float* out = (float*)d_out;

    hipLaunchKernelGGL(norm_kernel, dim3(NB * 64), dim3(64), 0, stream, x, ws);
    hipLaunchKernelGGL(mat_kernel, dim3(2304), dim3(256), 0, stream, x, ws);
    hipLaunchKernelGGL(gram_kernel, dim3(2048), dim3(256), 0, stream, ws);
    hipLaunchKernelGGL(attn_kernel, dim3(4096), dim3(256), 0, stream, x, ws, out);
}

// Round 10
// 777.690 us; speedup vs baseline: 1.5473x; 1.0393x over previous
//
#include <hip/hip_runtime.h>
#include <cstdint>

typedef short short8 __attribute__((ext_vector_type(8)));
typedef float f32x16 __attribute__((ext_vector_type(16)));

// Problem constants
#define NB 4
#define NN 4096
#define ND 576
#define BIGI 0x7FFFFFFF
#define NSLICE 16

// ws layout: A_hi (bf16) [b][tile32][kc18][512 chunks of 16B] = 9437184 shorts,
// then A_lo same size; then (float units):
#define INVN_OFF 9437184
#define CANDV_OFF 9439488
// CANDV: 4*16*4096*3 = 786432 floats -> ends at 10225920
#define CANDI_OFF 10225920
// CANDI: 786432 u16 = 393216 float-equiv -> total 10619136 floats = 42.5 MB (proven r8/r9)
//
// LANE-MAJOR region layout (new in r10): region (b,tile,kc) = 4096 shorts.
// chunk g = (sub*2 + h)*64 + lane, lane = kh2*32 + l31:
//   row = sub*32 + l31 (0..127), k_local = h*16 + kh2*8 .. +8.
// A frag load for (rowgroup sub, khalf h) = contiguous 1KB at base + lane*16B.

#define MFMA __builtin_amdgcn_mfma_f32_32x32x16_bf16

__device__ __forceinline__ unsigned short f2bf(float f) {
    unsigned u = __float_as_uint(f);
    u += 0x7FFFu + ((u >> 16) & 1u);   // round-to-nearest-even
    return (unsigned short)(u >> 16);
}

// Exact jax top_k comparator: bigger value wins; tie -> smaller index wins.
__device__ __forceinline__ void insert_cmp(float v, int m,
    float& v0, int& i0, float& v1, int& i1, float& v2, int& i2) {
    bool beat2 = (v > v2) || (v == v2 && m < i2);
    if (beat2) {
        bool beat1 = (v > v1) || (v == v1 && m < i1);
        if (beat1) {
            v2 = v1; i2 = i1;
            bool beat0 = (v > v0) || (v == v0 && m < i0);
            if (beat0) { v1 = v0; i1 = i0; v0 = v; i0 = m; }
            else       { v1 = v;  i1 = m; }
        } else { v2 = v; i2 = m; }
    }
}

// Kernel 1: per-(b,c) windowed sums of x^2 -> inv norms for the 9 kernel offsets.
__global__ __launch_bounds__(64) void norm_kernel(const float* __restrict__ x,
                                                  float* __restrict__ ws) {
    const int bc = blockIdx.x;          // b*64 + c
    const int lane = threadIdx.x;       // = column w
    const float* xp = x + ((size_t)bc << 12);
    float colsum = 0.f, v0 = 0.f, v63 = 0.f;
    for (int h = 0; h < 64; ++h) {
        const float val = xp[(h << 6) + lane];
        const float sq = val * val;
        colsum += sq;
        if (h == 0)  v0 = sq;
        if (h == 63) v63 = sq;
    }
    float total = colsum, row0 = v0, row63 = v63;
    #pragma unroll
    for (int o = 32; o > 0; o >>= 1) {
        total += __shfl_xor(total, o);
        row0  += __shfl_xor(row0, o);
        row63 += __shfl_xor(row63, o);
    }
    const float col0  = __shfl(colsum, 0);
    const float col63 = __shfl(colsum, 63);
    const float c00 = __shfl(v0, 0),  c0e = __shfl(v0, 63);
    const float ce0 = __shfl(v63, 0), cee = __shfl(v63, 63);
    if (lane < 9) {
        const int dh = lane / 3 - 1, dw = lane % 3 - 1;
        float S = total;
        if (dh == 1)  S -= row0;
        if (dh == -1) S -= row63;
        if (dw == 1)  S -= col0;
        if (dw == -1) S -= col63;
        if (dh == 1  && dw == 1)  S += c00;
        if (dh == 1  && dw == -1) S += c0e;
        if (dh == -1 && dw == 1)  S += ce0;
        if (dh == -1 && dw == -1) S += cee;
        float nrm = fmaxf(sqrtf(S), 1e-12f);
        ws[INVN_OFF + bc * 9 + lane] = 1.0f / nrm;
    }
}

// Kernel 2: split-bf16 materialization, LANE-MAJOR layout.
// blockIdx = (b*32+nt)*18+kc. Region = 512 chunks of 16B (8 bf16).
__global__ __launch_bounds__(256) void mat_kernel(const float* __restrict__ x,
                                                  float* __restrict__ ws) {
    const int bi = blockIdx.x;             // 2304 blocks
    const int b = bi / 576;
    const int rem = bi - b * 576;
    const int nt = rem / 18;
    const int kc = rem - nt * 18;
    unsigned short* AH = (unsigned short*)ws;
    unsigned short* AL = AH + 9437184;
    const float* invn = ws + INVN_OFF + b * 576;
    const int tid = threadIdx.x;
    #pragma unroll
    for (int hf2 = 0; hf2 < 2; ++hf2) {
        const int g = tid + hf2 * 256;     // output chunk 0..511
        const int lane6 = g & 63;
        const int hcl = (g >> 6) & 1;
        const int sub = g >> 7;
        const int row = sub * 32 + (lane6 & 31);
        const int k0 = hcl * 16 + (lane6 >> 5) * 8;
        const int n = nt * 128 + row;
        const int h = n >> 6, wc = n & 63;
        union { unsigned short us[8]; float4 f4; } uh, ul;
        #pragma unroll
        for (int j = 0; j < 8; ++j) {
            const int d = kc * 32 + k0 + j;
            const int ch = d / 9;
            const int p = d - ch * 9;
            const int r = h + p / 3 - 1, s2 = wc + p % 3 - 1;
            float val = 0.f;
            if ((unsigned)r < 64u && (unsigned)s2 < 64u)
                val = x[((size_t)(b * 64 + ch) << 12) + (r << 6) + s2];
            val *= invn[d];
            const unsigned short hb = f2bf(val);
            const float hfv = __uint_as_float(((unsigned)hb) << 16);
            const unsigned short lb = f2bf(val - hfv);
            uh.us[j] = hb; ul.us[j] = lb;
        }
        ((float4*)AH)[(size_t)bi * 512 + g] = uh.f4;
        ((float4*)AL)[(size_t)bi * 512 + g] = ul.f4;
    }
}

__device__ __forceinline__ short8 ldfragG(const unsigned short* p) {
    union { short8 s8; float4 f4; } u;
    u.f4 = *(const float4*)p;
    return u.s8;
}

// Kernel 3: R = A^T A via split-bf16 MFMA (hh + hl + lh), fused top-3.
// Zero-LDS K-loop, lane-major coalesced frag loads (1KB contiguous per instr),
// EXPLICIT register double-buffer at half-kc granularity: load set B (12 loads,
// MLP=12) while MFMAing set A (24 MFMA = 768 cyc covers ~700 cyc latency).
// Grid 2048 = 8 rounds x 256; XCD-rect as r9. Block: 128n x 256m, 4 waves,
// wave tile 128n x 64m (acc[2][4], 128 AGPR). ~240 unified regs -> 2 waves/EU.
// C/D: m_part = (reg&3)+8*(reg>>2)+4*(lane>>5), n_part = lane&31  [HW-verified r4]
__global__ void __launch_bounds__(256, 2) gram_kernel(float* ws) {
    __shared__ float cv[1536];
    __shared__ int   ci[1536];
    const int bx = blockIdx.x;
    const int r = bx >> 8;               // round 0..7
    const int t = bx & 255;
    const int x = t & 7, g = t >> 3;
    const int b = r >> 1;
    const int half = r & 1;
    const int nt = 16 * half + 4 * (x >> 1) + (g >> 3);   // 0..31
    const int ms = 8 * (x & 1) + (g & 7);                 // 0..15 (256-col slice)
    const int tid = threadIdx.x;
    const int w = tid >> 6, lane = tid & 63;
    const int l31 = lane & 31, kh2 = lane >> 5;

    const unsigned short* AH = (const unsigned short*)ws;
    const unsigned short* AL = AH + 9437184;

    // global bases (shorts), pre-offset by lane*8 (frag loads: base + const)
    const unsigned short* gAn[2];
    gAn[0] = AH + (size_t)((b * 32 + nt) * 18) * 4096 + lane * 8;
    gAn[1] = AL + (size_t)((b * 32 + nt) * 18) * 4096 + lane * 8;
    const unsigned short* gAm[2][2];     // [mi][plane]
    int subm[2];
    #pragma unroll
    for (int mi = 0; mi < 2; ++mi) {
        const int tile = 2 * ms + ((2 * w + mi) >> 2);
        subm[mi] = (2 * w + mi) & 3;
        gAm[mi][0] = AH + (size_t)((b * 32 + tile) * 18) * 4096 + lane * 8;
        gAm[mi][1] = AL + (size_t)((b * 32 + tile) * 18) * 4096 + lane * 8;
    }

    f32x16 acc[2][4];
    #pragma unroll
    for (int mi = 0; mi < 2; ++mi)
        #pragma unroll
        for (int ni = 0; ni < 4; ++ni)
            #pragma unroll
            for (int e = 0; e < 16; ++e) acc[mi][ni][e] = 0.f;

    // frag sets: [0..3]=An-hi(ni), [4..7]=An-lo(ni), [8..9]=Am-hi(mi), [10..11]=Am-lo(mi)
    short8 P0[12], P1[12];

    #define LOADSET(P, kc, h)                                                   \
        {                                                                       \
            const int kb_ = (kc) * 4096;                                        \
            _Pragma("unroll")                                                   \
            for (int ni = 0; ni < 4; ++ni) {                                    \
                P[ni]     = ldfragG(gAn[0] + kb_ + (ni * 2 + (h)) * 512);       \
                P[4 + ni] = ldfragG(gAn[1] + kb_ + (ni * 2 + (h)) * 512);       \
            }                                                                   \
            _Pragma("unroll")                                                   \
            for (int mi = 0; mi < 2; ++mi) {                                    \
                P[8 + mi]  = ldfragG(gAm[mi][0] + kb_ + (subm[mi] * 2 + (h)) * 512); \
                P[10 + mi] = ldfragG(gAm[mi][1] + kb_ + (subm[mi] * 2 + (h)) * 512); \
            }                                                                   \
        }

    #define COMPUTESET(P)                                                       \
        {                                                                       \
            _Pragma("unroll")                                                   \
            for (int ni = 0; ni < 4; ++ni)                                      \
                _Pragma("unroll")                                               \
                for (int mi = 0; mi < 2; ++mi) {                                \
                    acc[mi][ni] = MFMA(P[8 + mi],  P[ni],     acc[mi][ni], 0, 0, 0); \
                    acc[mi][ni] = MFMA(P[8 + mi],  P[4 + ni], acc[mi][ni], 0, 0, 0); \
                    acc[mi][ni] = MFMA(P[10 + mi], P[ni],     acc[mi][ni], 0, 0, 0); \
                }                                                               \
        }

    LOADSET(P0, 0, 0);
    for (int kc = 0; kc < 18; ++kc) {
        LOADSET(P1, kc, 1);
        COMPUTESET(P0);                 // (kc, h=0) — overlaps P1's latency
        if (kc < 17) LOADSET(P0, kc + 1, 0);
        COMPUTESET(P1);                 // (kc, h=1) — overlaps P0's latency
    }
    #undef LOADSET
    #undef COMPUTESET

    // fold acc into per-lane top-3 (per ni; n = nt*128 + ni*32 + l31)
    float t0v[4], t1v[4], t2v[4];
    int   t0i[4], t1i[4], t2i[4];
    #pragma unroll
    for (int i = 0; i < 4; ++i) {
        t0v[i] = t1v[i] = t2v[i] = -INFINITY;
        t0i[i] = t1i[i] = t2i[i] = BIGI;
    }
    const int mbase = ms * 256 + w * 64 + kh2 * 4;
    #pragma unroll
    for (int ni = 0; ni < 4; ++ni)
        #pragma unroll
        for (int mi = 0; mi < 2; ++mi)
            #pragma unroll
            for (int v = 0; v < 16; ++v) {
                const int m = mbase + mi * 32 + (v & 3) + 8 * (v >> 2);
                insert_cmp(acc[mi][ni][v], m,
                           t0v[ni], t0i[ni], t1v[ni], t1i[ni], t2v[ni], t2i[ni]);
            }

    // merge the two kh2 halves (same n, disjoint m) via shfl
    #pragma unroll
    for (int ni = 0; ni < 4; ++ni) {
        const float pv0 = __shfl_xor(t0v[ni], 32);
        const float pv1 = __shfl_xor(t1v[ni], 32);
        const float pv2 = __shfl_xor(t2v[ni], 32);
        const int pi0 = __shfl_xor(t0i[ni], 32);
        const int pi1 = __shfl_xor(t1i[ni], 32);
        const int pi2 = __shfl_xor(t2i[ni], 32);
        insert_cmp(pv0, pi0, t0v[ni], t0i[ni], t1v[ni], t1i[ni], t2v[ni], t2i[ni]);
        insert_cmp(pv1, pi1, t0v[ni], t0i[ni], t1v[ni], t1i[ni], t2v[ni], t2i[ni]);
        insert_cmp(pv2, pi2, t0v[ni], t0i[ni], t1v[ni], t1i[ni], t2v[ni], t2i[ni]);
    }
    // cross-wave merge through LDS (each wave owns a 64-wide m slice)
    __syncthreads();
    if (kh2 == 0) {
        #pragma unroll
        for (int ni = 0; ni < 4; ++ni) {
            const int base2 = ((w * 4 + ni) * 32 + l31) * 3;
            cv[base2] = t0v[ni]; cv[base2 + 1] = t1v[ni]; cv[base2 + 2] = t2v[ni];
            ci[base2] = t0i[ni]; ci[base2 + 1] = t1i[ni]; ci[base2 + 2] = t2i[ni];
        }
    }
    __syncthreads();
    if (tid < 128) {
        const int ni = tid >> 5, l = tid & 31;
        float v0 = -INFINITY, v1 = -INFINITY, v2 = -INFINITY;
        int i0 = BIGI, i1 = BIGI, i2 = BIGI;
        #pragma unroll
        for (int w2 = 0; w2 < 4; ++w2) {
            const int base2 = ((w2 * 4 + ni) * 32 + l) * 3;
            #pragma unroll
            for (int j = 0; j < 3; ++j)
                insert_cmp(cv[base2 + j], ci[base2 + j], v0, i0, v1, i1, v2, i2);
        }
        const int n_glob = nt * 128 + ni * 32 + l;
        const size_t o = ((size_t)(b * NSLICE + ms) * NN + n_glob) * 3;
        ws[CANDV_OFF + o] = v0; ws[CANDV_OFF + o + 1] = v1; ws[CANDV_OFF + o + 2] = v2;
        unsigned short* wi = (unsigned short*)(ws + CANDI_OFF);
        wi[o] = (unsigned short)i0; wi[o + 1] = (unsigned short)i1; wi[o + 2] = (unsigned short)i2;
    }
}

// Kernel 4: merge slice candidates -> global top-3; 27-way attention. One wave per n.
__global__ __launch_bounds__(256) void attn_kernel(const float* __restrict__ x,
                                                   const float* __restrict__ ws,
                                                   float* __restrict__ out) {
    const int wid = threadIdx.x >> 6;
    const int lane = threadIdx.x & 63;
    const int gw = blockIdx.x * 4 + wid;   // 0..16383
    const int b = gw >> 12;
    const int n = gw & 4095;

    float v0 = -INFINITY, v1 = -INFINITY, v2 = -INFINITY;
    int i0 = BIGI, i1 = BIGI, i2 = BIGI;
    const unsigned short* wi = (const unsigned short*)(ws + CANDI_OFF);
    for (int s = 0; s < NSLICE; ++s) {
        const size_t o = ((size_t)(b * NSLICE + s) * NN + n) * 3;
        #pragma unroll
        for (int j = 0; j < 3; ++j)
            insert_cmp(ws[CANDV_OFF + o + j], (int)wi[o + j], v0, i0, v1, i1, v2, i2);
    }
    const int idx3[3] = {i0, i1, i2};

    // per-lane feature meta for d = a*64 + lane  (torch reshape: K[...,a,c'] = xu[a*64+c'])
    int cc[9], dhh[9], dww[9];
    float inr[9];
    #pragma unroll
    for (int a = 0; a < 9; ++a) {
        const int d = a * 64 + lane;
        const int c = d / 9;
        const int p = d - c * 9;
        cc[a] = c; dhh[a] = p / 3 - 1; dww[a] = p - (p / 3) * 3 - 1;
        inr[a] = ws[INVN_OFF + b * ND + d];
    }
    const float q = x[((size_t)(b * 64 + lane) << 12) + n];

    float rv[27], sc[27];
    #pragma unroll
    for (int k = 0; k < 3; ++k) {
        const int m = idx3[k];
        const int hm = m >> 6, wm = m & 63;
        #pragma unroll
        for (int a = 0; a < 9; ++a) {
            const int r = hm + dhh[a], s2 = wm + dww[a];
            float val = 0.f;
            if ((unsigned)r < 64u && (unsigned)s2 < 64u)
                val = x[((size_t)(b * 64 + cc[a]) << 12) + (r << 6) + s2];
            const float rr = val * inr[a];
            rv[k * 9 + a] = rr;
            float t = q * rr;
            #pragma unroll
            for (int o2 = 32; o2 > 0; o2 >>= 1) t += __shfl_xor(t, o2);
            sc[k * 9 + a] = t * 0.125f;   // / sqrt(64)
        }
    }
    float mx = -INFINITY;
    #pragma unroll
    for (int u = 0; u < 27; ++u) mx = fmaxf(mx, sc[u]);
    float sum = 0.f;
    #pragma unroll
    for (int u = 0; u < 27; ++u) { const float e = expf(sc[u] - mx); sc[u] = e; sum += e; }
    const float inv = 1.0f / sum;
    float o = 0.f;
    #pragma unroll
    for (int u = 0; u < 27; ++u) o += sc[u] * rv[u];
    out[((size_t)gw << 6) + lane] = o * inv;
}

extern "C" void kernel_launch(void* const* d_in, const int* in_sizes, int n_in,
                              void* d_out, int out_size, void* d_ws, size_t ws_size,
                              hipStream_t stream) {
    (void)in_sizes; (void)n_in; (void)out_size; (void)ws_size;
    const float* x = (const float*)d_in[0];
    float* ws = (float*)d_ws;
    float* out = (float*)d_out;

    hipLaunchKernelGGL(norm_kernel, dim3(NB * 64), dim3(64), 0, stream, x, ws);
    hipLaunchKernelGGL(mat_kernel, dim3(2304), dim3(256), 0, stream, x, ws);
    hipLaunchKernelGGL(gram_kernel, dim3(2048), dim3(256), 0, stream, ws);
    hipLaunchKernelGGL(attn_kernel, dim3(4096), dim3(256), 0, stream, x, ws, out);
}